// Round 2
// baseline (5230.708 us; speedup 1.0000x reference)
//
#include <hip/hip_runtime.h>
#include <hip/hip_bf16.h>
#include <math.h>

#define N_NODES 50000
#define E_EDGES 400000
#define DIM 128
#define HEADS 8
#define CH 16
#define EDIM 64
#define HCDIM 128   // HEADS*CH

#define ECHUNK 50000     // edge chunk for attention passes (8 chunks)
#define FCHUNK 100000    // edge chunk for FFN (4 chunks)

// ---------------- utility kernels ----------------

__global__ void fill_kernel(float* p, float v, int n) {
    int i = blockIdx.x * blockDim.x + threadIdx.x;
    if (i < n) p[i] = v;
}

__device__ inline void atomicMaxFloat(float* addr, float v) {
    if (v >= 0.f) atomicMax((int*)addr, __float_as_int(v));
    else          atomicMin((unsigned int*)addr, __float_as_uint(v));
}

__device__ inline float gelu_f(float x) {
    return 0.5f * x * (1.0f + erff(x * 0.70710678118654752f));
}

__device__ inline float softplus_f(float x) {
    return x > 20.f ? x : log1pf(expf(x));
}

// ---------------- tiled fp32 GEMM: C = act(scale(A)(MxK) @ W(KxN) + bias) ----------------
// K % 16 == 0, N % 64 == 0. act: 0 = none, 1 = gelu.
// ascale (optional): per-row, per-16-col scale: A[r][k] *= ascale[r*(K/16) + k/16]
__global__ __launch_bounds__(256) void gemm_bias_act(
    const float* __restrict__ A, const float* __restrict__ W,
    const float* __restrict__ bias, const float* __restrict__ ascale,
    float* __restrict__ C, int M, int K, int Nc, int act)
{
    __shared__ float As[16][68];
    __shared__ float Ws[16][68];
    const int tid = threadIdx.x;
    const int m0 = blockIdx.y * 64;
    const int n0 = blockIdx.x * 64;
    const int tx = tid & 15;
    const int ty = tid >> 4;
    float acc[4][4] = {};

    const int am = tid >> 2, ak4 = (tid & 3) << 2;   // A tile load coords
    const int wk = tid >> 4, wn4 = (tid & 15) << 2;  // W tile load coords
    const int k16 = K >> 4;

    for (int k0 = 0; k0 < K; k0 += 16) {
        int ar = m0 + am;
        float4 av = make_float4(0.f, 0.f, 0.f, 0.f);
        if (ar < M) {
            av = *(const float4*)(A + (size_t)ar * K + k0 + ak4);
            if (ascale) {
                float s = ascale[(size_t)ar * k16 + (k0 >> 4)];
                av.x *= s; av.y *= s; av.z *= s; av.w *= s;
            }
        }
        As[ak4 + 0][am] = av.x;
        As[ak4 + 1][am] = av.y;
        As[ak4 + 2][am] = av.z;
        As[ak4 + 3][am] = av.w;
        float4 wv = *(const float4*)(W + (size_t)(k0 + wk) * Nc + n0 + wn4);
        *(float4*)&Ws[wk][wn4] = wv;
        __syncthreads();
#pragma unroll
        for (int kk = 0; kk < 16; ++kk) {
            float a0 = As[kk][ty * 4 + 0];
            float a1 = As[kk][ty * 4 + 1];
            float a2 = As[kk][ty * 4 + 2];
            float a3 = As[kk][ty * 4 + 3];
            float b0 = Ws[kk][tx * 4 + 0];
            float b1 = Ws[kk][tx * 4 + 1];
            float b2 = Ws[kk][tx * 4 + 2];
            float b3 = Ws[kk][tx * 4 + 3];
            acc[0][0] += a0 * b0; acc[0][1] += a0 * b1; acc[0][2] += a0 * b2; acc[0][3] += a0 * b3;
            acc[1][0] += a1 * b0; acc[1][1] += a1 * b1; acc[1][2] += a1 * b2; acc[1][3] += a1 * b3;
            acc[2][0] += a2 * b0; acc[2][1] += a2 * b1; acc[2][2] += a2 * b2; acc[2][3] += a2 * b3;
            acc[3][0] += a3 * b0; acc[3][1] += a3 * b1; acc[3][2] += a3 * b2; acc[3][3] += a3 * b3;
        }
        __syncthreads();
    }

    float4 bb = make_float4(0.f, 0.f, 0.f, 0.f);
    if (bias) bb = *(const float4*)(bias + n0 + tx * 4);
#pragma unroll
    for (int i = 0; i < 4; ++i) {
        int r = m0 + ty * 4 + i;
        if (r < M) {
            float4 o;
            o.x = acc[i][0] + bb.x;
            o.y = acc[i][1] + bb.y;
            o.z = acc[i][2] + bb.z;
            o.w = acc[i][3] + bb.w;
            if (act == 1) { o.x = gelu_f(o.x); o.y = gelu_f(o.y); o.z = gelu_f(o.z); o.w = gelu_f(o.w); }
            *(float4*)(C + (size_t)r * Nc + n0 + tx * 4) = o;
        }
    }
}

// ---------------- edge attention: logits (chunked over edges) ----------------
// one thread per (edge, head); eproj is chunk-local (rows e0..e0+ecnt)
__global__ __launch_bounds__(256) void edge_logits_kernel(
    const float* __restrict__ Q, const float* __restrict__ Kf,
    const float* __restrict__ eproj,
    const int* __restrict__ src, const int* __restrict__ dst,
    const float* __restrict__ Wke, const float* __restrict__ bke,
    float* __restrict__ logits, int e0, int ecnt)
{
    __shared__ float w1[256], w2[256], w3[256], bk[16];
    for (int i = threadIdx.x; i < 256; i += blockDim.x) {
        w1[i] = Wke[i];
        w2[i] = Wke[256 + i];
        w3[i] = Wke[512 + i];
    }
    if (threadIdx.x < 16) bk[threadIdx.x] = bke[threadIdx.x];
    __syncthreads();

    int idx = blockIdx.x * blockDim.x + threadIdx.x;
    if (idx >= ecnt * HEADS) return;
    int el = idx >> 3, h = idx & 7;
    int e = e0 + el;
    int s = src[e], d = dst[e];

    const float* kd = Kf + (size_t)d * HCDIM + h * CH;
    const float* ks = Kf + (size_t)s * HCDIM + h * CH;
    const float* ee = eproj + (size_t)el * HCDIM + h * CH;
    const float* qd = Q + (size_t)d * HCDIM + h * CH;

    float kdv[16], ksv[16], ev[16], qv[16];
#pragma unroll
    for (int q4 = 0; q4 < 4; ++q4) {
        *(float4*)&kdv[q4 * 4] = *(const float4*)(kd + q4 * 4);
        *(float4*)&ksv[q4 * 4] = *(const float4*)(ks + q4 * 4);
        *(float4*)&ev[q4 * 4]  = *(const float4*)(ee + q4 * 4);
        *(float4*)&qv[q4 * 4]  = *(const float4*)(qd + q4 * 4);
    }

    float logit = 0.f;
#pragma unroll
    for (int j = 0; j < 16; ++j) {
        float kn = bk[j];
#pragma unroll
        for (int c = 0; c < 16; ++c)
            kn += kdv[c] * w1[c * 16 + j] + ksv[c] * w2[c * 16 + j] + ev[c] * w3[c * 16 + j];
        logit += qv[j] * kn;
    }
    logits[(size_t)e * HEADS + h] = logit * 0.25f;   // 1/sqrt(16)
}

__global__ __launch_bounds__(256) void seg_max_kernel(
    const float* __restrict__ logits, const int* __restrict__ dst,
    float* __restrict__ mx)
{
    int idx = blockIdx.x * blockDim.x + threadIdx.x;
    if (idx >= E_EDGES * HEADS) return;
    int e = idx >> 3, h = idx & 7;
    atomicMaxFloat(&mx[(size_t)dst[e] * HEADS + h], logits[idx]);
}

__global__ __launch_bounds__(256) void seg_expsum_kernel(
    float* __restrict__ logits /* in-place -> ex */, const int* __restrict__ dst,
    const float* __restrict__ mx, float* __restrict__ den)
{
    int idx = blockIdx.x * blockDim.x + threadIdx.x;
    if (idx >= E_EDGES * HEADS) return;
    int e = idx >> 3, h = idx & 7;
    int d = dst[e];
    float ex = expf(logits[idx] - mx[(size_t)d * HEADS + h]);
    logits[idx] = ex;
    atomicAdd(&den[(size_t)d * HEADS + h], ex);
}

// ---------------- edge attention: Vnew * alpha aggregation; alpha stored in-place ----------------
__global__ __launch_bounds__(256) void edge_v_msg_kernel(
    const float* __restrict__ V, const float* __restrict__ eproj,
    float* __restrict__ exalpha /* in: ex, out: alpha */, const float* __restrict__ den,
    const int* __restrict__ src, const int* __restrict__ dst,
    const float* __restrict__ Wve, const float* __restrict__ bve,
    float* __restrict__ aggout, int e0, int ecnt)
{
    __shared__ float w1[256], w2[256], w3[256], bv[16];
    for (int i = threadIdx.x; i < 256; i += blockDim.x) {
        w1[i] = Wve[i];
        w2[i] = Wve[256 + i];
        w3[i] = Wve[512 + i];
    }
    if (threadIdx.x < 16) bv[threadIdx.x] = bve[threadIdx.x];
    __syncthreads();

    int idx = blockIdx.x * blockDim.x + threadIdx.x;
    if (idx >= ecnt * HEADS) return;
    int el = idx >> 3, h = idx & 7;
    int e = e0 + el;
    int s = src[e], d = dst[e];

    size_t li = (size_t)e * HEADS + h;
    float alpha = exalpha[li] / (den[(size_t)d * HEADS + h] + 1e-16f);
    exalpha[li] = alpha;

    const float* vd = V + (size_t)d * HCDIM + h * CH;
    const float* vs = V + (size_t)s * HCDIM + h * CH;
    const float* ee = eproj + (size_t)el * HCDIM + h * CH;

    float vdv[16], vsv[16], ev[16];
#pragma unroll
    for (int q4 = 0; q4 < 4; ++q4) {
        *(float4*)&vdv[q4 * 4] = *(const float4*)(vd + q4 * 4);
        *(float4*)&vsv[q4 * 4] = *(const float4*)(vs + q4 * 4);
        *(float4*)&ev[q4 * 4]  = *(const float4*)(ee + q4 * 4);
    }

    float* aggp = aggout + (size_t)d * HCDIM + h * CH;
#pragma unroll
    for (int j = 0; j < 16; ++j) {
        float vn = bv[j];
#pragma unroll
        for (int c = 0; c < 16; ++c)
            vn += vdv[c] * w1[c * 16 + j] + vsv[c] * w2[c * 16 + j] + ev[c] * w3[c * 16 + j];
        atomicAdd(&aggp[j], vn * alpha);
    }
}

// ---------------- layernorm (+ residual), in-place, one wave per row ----------------
__global__ __launch_bounds__(256) void ln_res_kernel(
    float* __restrict__ y, const float* __restrict__ g, const float* __restrict__ b,
    const float* __restrict__ res, int rows, int w)
{
    int wave = threadIdx.x >> 6;
    int lane = threadIdx.x & 63;
    int nw = blockDim.x >> 6;
    for (int r = blockIdx.x * nw + wave; r < rows; r += gridDim.x * nw) {
        size_t base = (size_t)r * w;
        float v0 = y[base + lane];
        float v1 = (w == 128) ? y[base + 64 + lane] : 0.f;
        float s = v0 + v1;
#pragma unroll
        for (int o = 32; o; o >>= 1) s += __shfl_xor(s, o);
        float m = s / (float)w;
        float d0 = v0 - m;
        float d1 = (w == 128) ? (v1 - m) : 0.f;
        float q = d0 * d0 + d1 * d1;
#pragma unroll
        for (int o = 32; o; o >>= 1) q += __shfl_xor(q, o);
        float inv = rsqrtf(q / (float)w + 1e-5f);
        y[base + lane] = d0 * inv * g[lane] + b[lane] + res[base + lane];
        if (w == 128)
            y[base + 64 + lane] = d1 * inv * g[64 + lane] + b[64 + lane] + res[base + 64 + lane];
    }
}

// ---------------- batchnorm stats ----------------
__global__ __launch_bounds__(256) void bn_stats_kernel(
    const float* __restrict__ y, float* __restrict__ colsum, float* __restrict__ colsq,
    int rows, int cols)
{
    __shared__ float ss[256], sq[256];
    int tid = threadIdx.x;
    int col = tid % cols;
    int rsub = tid / cols;
    int rstep = blockDim.x / cols;
    float ls = 0.f, lq = 0.f;
    for (int r = blockIdx.x * rstep + rsub; r < rows; r += gridDim.x * rstep) {
        float v = y[(size_t)r * cols + col];
        ls += v;
        lq += v * v;
    }
    ss[tid] = ls;
    sq[tid] = lq;
    __syncthreads();
    if (tid < cols) {
        for (int o = cols; o < 256; o += cols) { ls += ss[tid + o]; lq += sq[tid + o]; }
        atomicAdd(&colsum[tid], ls);
        atomicAdd(&colsq[tid], lq);
    }
}

// ---------------- batchnorm apply + residual + softplus -> output ----------------
__global__ __launch_bounds__(256) void bn_apply_softplus_kernel(
    const float* __restrict__ y, const float* __restrict__ res,
    const float* __restrict__ colsum, const float* __restrict__ colsq,
    const float* __restrict__ g, const float* __restrict__ b,
    float* __restrict__ out, int rows, int cols)
{
    int idx = blockIdx.x * blockDim.x + threadIdx.x;
    int n = rows * cols;
    if (idx >= n) return;
    int c = idx % cols;
    float m = colsum[c] / (float)rows;
    float var = colsq[c] / (float)rows - m * m;
    float inv = rsqrtf(var + 1e-5f);
    float v = (y[idx] - m) * inv * g[c] + b[c] + res[idx];
    out[idx] = softplus_f(v);
}

// ---------------- launcher ----------------

extern "C" void kernel_launch(void* const* d_in, const int* in_sizes, int n_in,
                              void* d_out, int out_size, void* d_ws, size_t ws_size,
                              hipStream_t stream) {
    const float* x         = (const float*)d_in[0];
    const int*   ei        = (const int*)d_in[1];
    const float* edge_attr = (const float*)d_in[2];
    const float* Wq  = (const float*)d_in[3];
    const float* bq  = (const float*)d_in[4];
    const float* Wk  = (const float*)d_in[5];
    const float* bk  = (const float*)d_in[6];
    const float* Wv  = (const float*)d_in[7];
    const float* bv  = (const float*)d_in[8];
    const float* We  = (const float*)d_in[9];
    const float* Wke = (const float*)d_in[10];
    const float* bke = (const float*)d_in[11];
    const float* Wve = (const float*)d_in[12];
    const float* bve = (const float*)d_in[13];
    const float* Wfce = (const float*)d_in[14];
    const float* bfce = (const float*)d_in[15];
    const float* lne_g = (const float*)d_in[16];
    const float* lne_b = (const float*)d_in[17];
    const float* Wfcn = (const float*)d_in[18];
    const float* bfcn = (const float*)d_in[19];
    const float* lnn_g = (const float*)d_in[20];
    const float* lnn_b = (const float*)d_in[21];
    const float* W1n = (const float*)d_in[22];
    const float* b1n = (const float*)d_in[23];
    const float* W2n = (const float*)d_in[24];
    const float* b2n = (const float*)d_in[25];
    const float* W1e = (const float*)d_in[26];
    const float* b1e = (const float*)d_in[27];
    const float* W2e = (const float*)d_in[28];
    const float* b2e = (const float*)d_in[29];
    const float* bnn_g = (const float*)d_in[30];
    const float* bnn_b = (const float*)d_in[31];
    const float* bne_g = (const float*)d_in[32];
    const float* bne_b = (const float*)d_in[33];

    const int* src = ei;
    const int* dst = ei + E_EDGES;

    float* ws = (float*)d_ws;

    // ---- compact workspace: 76.8M floats + 512 ≈ 307 MB ----
    const size_t M64   = (size_t)E_EDGES * EDIM;       // 25.6M
    const size_t NODE2 = (size_t)N_NODES * HCDIM;      // 6.4M

    // regionR [0, 25.6M): phase A = Qb|Kb|Vb|eproj_chunk; phase B = h_n; phase C = h_e chunk
    float* regionR = ws;
    float* Qb  = regionR;
    float* Kb  = regionR + NODE2;
    float* Vb  = regionR + 2 * NODE2;
    float* eproj_c = regionR + 3 * NODE2;              // 6.4M chunk (ECHUNK x 128)
    float* h_n = regionR;                              // 25.6M (N x 512)
    float* h_e = regionR;                              // 25.6M (FCHUNK x 256)

    // overlayY [25.6M, 51.2M): phase A/B = logits|mx|den|aggout|y_n|x_out; phase C = y_e
    float* overlayY = ws + M64;
    float* logits = overlayY;                                  // 3.2M
    float* mx     = overlayY + (size_t)E_EDGES * HEADS;        // 0.4M
    float* den    = mx + (size_t)N_NODES * HEADS;              // 0.4M
    float* aggout = den + (size_t)N_NODES * HEADS;             // 6.4M
    float* y_n    = aggout + NODE2;                            // 6.4M
    float* x_out  = y_n + NODE2;                               // 6.4M  (ends at 23.2M < 25.6M)
    float* y_e    = overlayY;                                  // 25.6M

    // e_out [51.2M, 76.8M)
    float* e_out = ws + 2 * M64;

    // colsums [76.8M, +384)
    float* colsum_n = ws + 3 * M64;
    float* colsq_n  = colsum_n + 128;
    float* colsum_e = colsq_n + 128;
    float* colsq_e  = colsum_e + 64;

    const int EH = E_EDGES * HEADS;
    dim3 blk(256);

    // ---- init ----
    {
        int n = N_NODES * HEADS;
        fill_kernel<<<dim3((n + 255) / 256), blk, 0, stream>>>(mx, -INFINITY, n);
        fill_kernel<<<dim3((n + 255) / 256), blk, 0, stream>>>(den, 0.f, n);
        int n2 = N_NODES * HCDIM;
        fill_kernel<<<dim3((n2 + 255) / 256), blk, 0, stream>>>(aggout, 0.f, n2);
        fill_kernel<<<dim3(2), blk, 0, stream>>>(colsum_n, 0.f, 384);
    }

    // ---- QKV projections ----
    gemm_bias_act<<<dim3(HCDIM / 64, (N_NODES + 63) / 64), blk, 0, stream>>>(x, Wq, bq, nullptr, Qb, N_NODES, DIM, HCDIM, 0);
    gemm_bias_act<<<dim3(HCDIM / 64, (N_NODES + 63) / 64), blk, 0, stream>>>(x, Wk, bk, nullptr, Kb, N_NODES, DIM, HCDIM, 0);
    gemm_bias_act<<<dim3(HCDIM / 64, (N_NODES + 63) / 64), blk, 0, stream>>>(x, Wv, bv, nullptr, Vb, N_NODES, DIM, HCDIM, 0);

    // ---- attention pass 1: logits per edge chunk ----
    for (int e0 = 0; e0 < E_EDGES; e0 += ECHUNK) {
        gemm_bias_act<<<dim3(HCDIM / 64, (ECHUNK + 63) / 64), blk, 0, stream>>>(
            edge_attr + (size_t)e0 * EDIM, We, nullptr, nullptr, eproj_c, ECHUNK, EDIM, HCDIM, 0);
        edge_logits_kernel<<<dim3((ECHUNK * HEADS + 255) / 256), blk, 0, stream>>>(
            Qb, Kb, eproj_c, src, dst, Wke, bke, logits, e0, ECHUNK);
    }

    // ---- segment softmax ----
    seg_max_kernel<<<dim3((EH + 255) / 256), blk, 0, stream>>>(logits, dst, mx);
    seg_expsum_kernel<<<dim3((EH + 255) / 256), blk, 0, stream>>>(logits, dst, mx, den);

    // ---- attention pass 2: Vnew*alpha aggregation + e_out pre-LN (fused alpha) ----
    for (int e0 = 0; e0 < E_EDGES; e0 += ECHUNK) {
        gemm_bias_act<<<dim3(HCDIM / 64, (ECHUNK + 63) / 64), blk, 0, stream>>>(
            edge_attr + (size_t)e0 * EDIM, We, nullptr, nullptr, eproj_c, ECHUNK, EDIM, HCDIM, 0);
        edge_v_msg_kernel<<<dim3((ECHUNK * HEADS + 255) / 256), blk, 0, stream>>>(
            Vb, eproj_c, logits, den, src, dst, Wve, bve, aggout, e0, ECHUNK);
        // e_out[e0:e0+ECHUNK] = (eproj * alpha) @ Wfce + bfce
        gemm_bias_act<<<dim3(EDIM / 64, (ECHUNK + 63) / 64), blk, 0, stream>>>(
            eproj_c, Wfce, bfce, logits + (size_t)e0 * HEADS,
            e_out + (size_t)e0 * EDIM, ECHUNK, HCDIM, EDIM, 0);
    }
    ln_res_kernel<<<dim3(25000), blk, 0, stream>>>(e_out, lne_g, lne_b, edge_attr, E_EDGES, EDIM);

    // ---- node output path ----
    gemm_bias_act<<<dim3(DIM / 64, (N_NODES + 63) / 64), blk, 0, stream>>>(aggout, Wfcn, bfcn, nullptr, x_out, N_NODES, HCDIM, DIM, 0);
    ln_res_kernel<<<dim3(12500), blk, 0, stream>>>(x_out, lnn_g, lnn_b, x, N_NODES, DIM);

    // ---- node FFN + BN + residual + softplus (h_n overlays Q/K/V/eproj_c) ----
    gemm_bias_act<<<dim3(4 * DIM / 64, (N_NODES + 63) / 64), blk, 0, stream>>>(x_out, W1n, b1n, nullptr, h_n, N_NODES, DIM, 4 * DIM, 1);
    gemm_bias_act<<<dim3(DIM / 64, (N_NODES + 63) / 64), blk, 0, stream>>>(h_n, W2n, b2n, nullptr, y_n, N_NODES, 4 * DIM, DIM, 0);
    bn_stats_kernel<<<dim3(256), blk, 0, stream>>>(y_n, colsum_n, colsq_n, N_NODES, DIM);
    {
        int n = N_NODES * DIM;
        bn_apply_softplus_kernel<<<dim3((n + 255) / 256), blk, 0, stream>>>(
            y_n, x_out, colsum_n, colsq_n, bnn_g, bnn_b, (float*)d_out, N_NODES, DIM);
    }

    // ---- edge FFN (chunked; h_e overlays regionR, y_e overlays overlayY) ----
    for (int f0 = 0; f0 < E_EDGES; f0 += FCHUNK) {
        gemm_bias_act<<<dim3(4 * EDIM / 64, (FCHUNK + 63) / 64), blk, 0, stream>>>(
            e_out + (size_t)f0 * EDIM, W1e, b1e, nullptr, h_e, FCHUNK, EDIM, 4 * EDIM, 1);
        gemm_bias_act<<<dim3(EDIM / 64, (FCHUNK + 63) / 64), blk, 0, stream>>>(
            h_e, W2e, b2e, nullptr, y_e + (size_t)f0 * EDIM, FCHUNK, 4 * EDIM, EDIM, 0);
    }
    bn_stats_kernel<<<dim3(256), blk, 0, stream>>>(y_e, colsum_e, colsq_e, E_EDGES, EDIM);
    {
        int n = E_EDGES * EDIM;
        bn_apply_softplus_kernel<<<dim3((n + 255) / 256), blk, 0, stream>>>(
            y_e, e_out, colsum_e, colsq_e, bne_g, bne_b, (float*)d_out + (size_t)N_NODES * DIM, E_EDGES, EDIM);
    }
}

// Round 3
// 2630.318 us; speedup vs baseline: 1.9886x; 1.9886x over previous
//
#include <hip/hip_runtime.h>
#include <hip/hip_bf16.h>
#include <math.h>

#define N_NODES 50000
#define E_EDGES 400000
#define DIM 128
#define HEADS 8
#define CH 16
#define EDIM 64
#define HCDIM 128   // HEADS*CH

#define ECHUNK 50000     // edge chunk for eproj recompute (8 chunks)
#define FCHUNK 100000    // edge chunk for FFN (4 chunks)
#define NODE_WAVES 4

// ---------------- utility kernels ----------------

__global__ void fill_kernel(float* p, float v, int n) {
    int i = blockIdx.x * blockDim.x + threadIdx.x;
    if (i < n) p[i] = v;
}

__device__ inline float gelu_f(float x) {
    return 0.5f * x * (1.0f + erff(x * 0.70710678118654752f));
}

__device__ inline float softplus_f(float x) {
    return x > 20.f ? x : log1pf(expf(x));
}

// ---------------- tiled fp32 GEMM: C = act(scale(A)(MxK) @ W(KxN) + bias) ----------------
// K % 16 == 0, N % 64 == 0. act: 0 = none, 1 = gelu.
// ascale (optional): per-row, per-16-col scale: A[r][k] *= ascale[r*(K/16) + k/16]
__global__ __launch_bounds__(256) void gemm_bias_act(
    const float* __restrict__ A, const float* __restrict__ W,
    const float* __restrict__ bias, const float* __restrict__ ascale,
    float* __restrict__ C, int M, int K, int Nc, int act)
{
    __shared__ float As[16][68];
    __shared__ float Ws[16][68];
    const int tid = threadIdx.x;
    const int m0 = blockIdx.y * 64;
    const int n0 = blockIdx.x * 64;
    const int tx = tid & 15;
    const int ty = tid >> 4;
    float acc[4][4] = {};

    const int am = tid >> 2, ak4 = (tid & 3) << 2;   // A tile load coords
    const int wk = tid >> 4, wn4 = (tid & 15) << 2;  // W tile load coords
    const int k16 = K >> 4;

    for (int k0 = 0; k0 < K; k0 += 16) {
        int ar = m0 + am;
        float4 av = make_float4(0.f, 0.f, 0.f, 0.f);
        if (ar < M) {
            av = *(const float4*)(A + (size_t)ar * K + k0 + ak4);
            if (ascale) {
                float s = ascale[(size_t)ar * k16 + (k0 >> 4)];
                av.x *= s; av.y *= s; av.z *= s; av.w *= s;
            }
        }
        As[ak4 + 0][am] = av.x;
        As[ak4 + 1][am] = av.y;
        As[ak4 + 2][am] = av.z;
        As[ak4 + 3][am] = av.w;
        float4 wv = *(const float4*)(W + (size_t)(k0 + wk) * Nc + n0 + wn4);
        *(float4*)&Ws[wk][wn4] = wv;
        __syncthreads();
#pragma unroll
        for (int kk = 0; kk < 16; ++kk) {
            float a0 = As[kk][ty * 4 + 0];
            float a1 = As[kk][ty * 4 + 1];
            float a2 = As[kk][ty * 4 + 2];
            float a3 = As[kk][ty * 4 + 3];
            float b0 = Ws[kk][tx * 4 + 0];
            float b1 = Ws[kk][tx * 4 + 1];
            float b2 = Ws[kk][tx * 4 + 2];
            float b3 = Ws[kk][tx * 4 + 3];
            acc[0][0] += a0 * b0; acc[0][1] += a0 * b1; acc[0][2] += a0 * b2; acc[0][3] += a0 * b3;
            acc[1][0] += a1 * b0; acc[1][1] += a1 * b1; acc[1][2] += a1 * b2; acc[1][3] += a1 * b3;
            acc[2][0] += a2 * b0; acc[2][1] += a2 * b1; acc[2][2] += a2 * b2; acc[2][3] += a2 * b3;
            acc[3][0] += a3 * b0; acc[3][1] += a3 * b1; acc[3][2] += a3 * b2; acc[3][3] += a3 * b3;
        }
        __syncthreads();
    }

    float4 bb = make_float4(0.f, 0.f, 0.f, 0.f);
    if (bias) bb = *(const float4*)(bias + n0 + tx * 4);
#pragma unroll
    for (int i = 0; i < 4; ++i) {
        int r = m0 + ty * 4 + i;
        if (r < M) {
            float4 o;
            o.x = acc[i][0] + bb.x;
            o.y = acc[i][1] + bb.y;
            o.z = acc[i][2] + bb.z;
            o.w = acc[i][3] + bb.w;
            if (act == 1) { o.x = gelu_f(o.x); o.y = gelu_f(o.y); o.z = gelu_f(o.z); o.w = gelu_f(o.w); }
            *(float4*)(C + (size_t)r * Nc + n0 + tx * 4) = o;
        }
    }
}

// ---------------- precompute: WeX[k][h*16+j] = sum_c We[k][h*16+c] * X[c][j] ----------------
// X is a 16x16 matrix (Wk3 or Wv3). out is 64x128.
__global__ __launch_bounds__(256) void wex_kernel(
    const float* __restrict__ We, const float* __restrict__ X, float* __restrict__ out)
{
    int idx = blockIdx.x * 256 + threadIdx.x;
    if (idx >= 64 * 128) return;
    int k = idx >> 7, hj = idx & 127, h = hj >> 4, j = hj & 15;
    float s = 0.f;
#pragma unroll
    for (int c = 0; c < 16; ++c) s += We[k * 128 + h * 16 + c] * X[c * 16 + j];
    out[idx] = s;
}

// ---------------- precompute per (d,h): c0 = Q·(K@Wk1 + bke); A2[c] = sum_j Wk2[c][j]*Q[j] ----------------
__global__ __launch_bounds__(256) void qk_pre_kernel(
    const float* __restrict__ Q, const float* __restrict__ K,
    const float* __restrict__ Wke, const float* __restrict__ bke,
    float* __restrict__ A2, float* __restrict__ c0)
{
    __shared__ float wk1[256], wk2[256], bks[16];
    for (int i = threadIdx.x; i < 256; i += 256) { wk1[i] = Wke[i]; wk2[i] = Wke[256 + i]; }
    if (threadIdx.x < 16) bks[threadIdx.x] = bke[threadIdx.x];
    __syncthreads();
    int idx = blockIdx.x * 256 + threadIdx.x;   // idx = ((d*8 + h)*16 + j)
    int j = idx & 15; int dh = idx >> 4; int h = dh & 7; int d = dh >> 3;
    if (d >= N_NODES) return;
    const float* q = Q + (size_t)d * HCDIM + h * CH;
    const float* k = K + (size_t)d * HCDIM + h * CH;
    float qv[16], kv[16];
#pragma unroll
    for (int t = 0; t < 4; ++t) {
        *(float4*)&qv[t * 4] = *(const float4*)(q + t * 4);
        *(float4*)&kv[t * 4] = *(const float4*)(k + t * 4);
    }
    float a2 = 0.f;
#pragma unroll
    for (int t = 0; t < 16; ++t) a2 += wk2[j * 16 + t] * qv[t];
    A2[idx] = a2;
    float kn = bks[j];
#pragma unroll
    for (int c = 0; c < 16; ++c) kn += kv[c] * wk1[c * 16 + j];
    float t = qv[j] * kn;
    t += __shfl_xor(t, 1); t += __shfl_xor(t, 2); t += __shfl_xor(t, 4); t += __shfl_xor(t, 8);
    if (j == 0) c0[dh] = t;
}

// ---------------- logits (chunked): logit = 0.25*(c0[d,h] + A2[d,h]·K[s,h] + Q[d,h]·eproj3[e,h]) ----------------
__global__ __launch_bounds__(256) void logits_kernel(
    const float* __restrict__ Q, const float* __restrict__ K,
    const float* __restrict__ A2, const float* __restrict__ c0,
    const float* __restrict__ ep3,
    const int* __restrict__ src, const int* __restrict__ dst,
    float* __restrict__ logits, int e0, int ecnt)
{
    int idx = blockIdx.x * 256 + threadIdx.x;
    if (idx >= ecnt * HEADS) return;
    int el = idx >> 3, h = idx & 7, e = e0 + el;
    int s = src[e], d = dst[e];
    const float* q  = Q  + (size_t)d * HCDIM + h * CH;
    const float* a2 = A2 + (size_t)d * HCDIM + h * CH;
    const float* ks = K  + (size_t)s * HCDIM + h * CH;
    const float* ep = ep3 + (size_t)el * HCDIM + h * CH;
    float acc = c0[(size_t)d * HEADS + h];
    float qv[16], av[16], kv[16], ev[16];
#pragma unroll
    for (int t = 0; t < 4; ++t) {
        *(float4*)&qv[t * 4] = *(const float4*)(q + t * 4);
        *(float4*)&av[t * 4] = *(const float4*)(a2 + t * 4);
        *(float4*)&kv[t * 4] = *(const float4*)(ks + t * 4);
        *(float4*)&ev[t * 4] = *(const float4*)(ep + t * 4);
    }
#pragma unroll
    for (int t = 0; t < 16; ++t) acc += av[t] * kv[t] + qv[t] * ev[t];
    logits[(size_t)e * HEADS + h] = acc * 0.25f;
}

// ---------------- CSR build ----------------
__global__ __launch_bounds__(256) void count_kernel(const int* __restrict__ dst, int* __restrict__ cnt) {
    int e = blockIdx.x * 256 + threadIdx.x;
    if (e < E_EDGES) atomicAdd(&cnt[dst[e]], 1);
}

__global__ __launch_bounds__(1024) void scan_kernel(
    const int* __restrict__ cnt, int* __restrict__ rowptr, int* __restrict__ cursor, int n)
{
    __shared__ int buf[1024];
    __shared__ int base;
    int tid = threadIdx.x;
    if (tid == 0) { base = 0; rowptr[0] = 0; }
    __syncthreads();
    for (int t0 = 0; t0 < n; t0 += 1024) {
        int i = t0 + tid;
        int v = (i < n) ? cnt[i] : 0;
        buf[tid] = v;
        __syncthreads();
        for (int off = 1; off < 1024; off <<= 1) {
            int add = (tid >= off) ? buf[tid - off] : 0;
            __syncthreads();
            buf[tid] += add;
            __syncthreads();
        }
        if (i < n) { rowptr[i + 1] = base + buf[tid]; cursor[i] = base + buf[tid] - v; }
        __syncthreads();
        if (tid == 0) base += buf[1023];
        __syncthreads();
    }
}

__global__ __launch_bounds__(256) void scatter_kernel(
    const int* __restrict__ dst, int* __restrict__ cursor, int* __restrict__ eidx) {
    int e = blockIdx.x * 256 + threadIdx.x;
    if (e < E_EDGES) {
        int p = atomicAdd(&cursor[dst[e]], 1);
        eidx[p] = e;
    }
}

// ---------------- per-node attention: softmax + gather-aggregate + Wv transforms ----------------
// one wave per node. logits -> alpha (in place). aggout[d] = full Vnew-weighted sum.
__global__ __launch_bounds__(256) void node_attn_kernel(
    const float* __restrict__ Vb, const float* __restrict__ edge_attr,
    float* __restrict__ logits,
    const int* __restrict__ rowptr, const int* __restrict__ eidx,
    const int* __restrict__ src,
    const float* __restrict__ Wve, const float* __restrict__ bve,
    const float* __restrict__ WeWv3, float* __restrict__ aggout)
{
    __shared__ float w3s[64 * 128];
    __shared__ float wv1s[256], wv2s[256], bvs[16];
    __shared__ float stage[NODE_WAVES][640];   // per wave: wea[8][64] then aggv[8][16]

    for (int i = threadIdx.x; i < 64 * 128; i += 256) w3s[i] = WeWv3[i];
    for (int i = threadIdx.x; i < 256; i += 256) { wv1s[i] = Wve[i]; wv2s[i] = Wve[256 + i]; }
    if (threadIdx.x < 16) bvs[threadIdx.x] = bve[threadIdx.x];
    __syncthreads();

    int w = threadIdx.x >> 6, lane = threadIdx.x & 63;
    int d = blockIdx.x * NODE_WAVES + w;
    int r0 = rowptr[d], r1 = rowptr[d + 1], deg = r1 - r0;
    int h = lane >> 3, kg = lane & 7;

    if (deg == 0) {
        aggout[(size_t)d * HCDIM + lane] = 0.f;
        aggout[(size_t)d * HCDIM + 64 + lane] = 0.f;
    } else {
        // softmax stats, all 8 heads per lane
        float m[8], ssum[8];
#pragma unroll
        for (int t = 0; t < 8; ++t) { m[t] = -INFINITY; ssum[t] = 0.f; }
        for (int i = r0 + lane; i < r1; i += 64) {
            int e = eidx[i];
            const float* lp = logits + (size_t)e * HEADS;
            float l[8];
            *(float4*)&l[0] = *(const float4*)lp;
            *(float4*)&l[4] = *(const float4*)(lp + 4);
#pragma unroll
            for (int t = 0; t < 8; ++t) m[t] = fmaxf(m[t], l[t]);
        }
#pragma unroll
        for (int o = 1; o < 64; o <<= 1) {
#pragma unroll
            for (int t = 0; t < 8; ++t) m[t] = fmaxf(m[t], __shfl_xor(m[t], o));
        }
        for (int i = r0 + lane; i < r1; i += 64) {
            int e = eidx[i];
            const float* lp = logits + (size_t)e * HEADS;
            float l[8];
            *(float4*)&l[0] = *(const float4*)lp;
            *(float4*)&l[4] = *(const float4*)(lp + 4);
#pragma unroll
            for (int t = 0; t < 8; ++t) ssum[t] += expf(l[t] - m[t]);
        }
#pragma unroll
        for (int o = 1; o < 64; o <<= 1) {
#pragma unroll
            for (int t = 0; t < 8; ++t) ssum[t] += __shfl_xor(ssum[t], o);
        }
        // select this lane's head stats (avoid dynamic register indexing)
        float mh = m[0], dd = ssum[0];
#pragma unroll
        for (int t = 1; t < 8; ++t) { if (h == t) { mh = m[t]; dd = ssum[t]; } }
        float den = dd + 1e-16f;

        // aggregation: all 64 lanes cooperate per edge
        float wea[8] = {0.f, 0.f, 0.f, 0.f, 0.f, 0.f, 0.f, 0.f};
        float av0 = 0.f, av1 = 0.f;
        for (int i = r0; i < r1; ++i) {
            int e = eidx[i];
            float lg = logits[(size_t)e * HEADS + h];
            float alpha = expf(lg - mh) / den;
            if (kg == 0) logits[(size_t)e * HEADS + h] = alpha;   // store alpha for e_out path
            int s = src[e];
            const float* ea = edge_attr + (size_t)e * EDIM + kg * 8;
            float ev[8];
            *(float4*)&ev[0] = *(const float4*)ea;
            *(float4*)&ev[4] = *(const float4*)(ea + 4);
#pragma unroll
            for (int t = 0; t < 8; ++t) wea[t] += alpha * ev[t];
            float2 vv = *(const float2*)(Vb + (size_t)s * HCDIM + h * CH + kg * 2);
            av0 += alpha * vv.x;
            av1 += alpha * vv.y;
        }
        float* st = stage[w];
#pragma unroll
        for (int t = 0; t < 8; ++t) st[h * 64 + kg * 8 + t] = wea[t];
        st[512 + h * 16 + kg * 2] = av0;
        st[512 + h * 16 + kg * 2 + 1] = av1;
    }
    __syncthreads();
    if (deg > 0) {
        float* st = stage[w];
        int c0i = kg * 2;
        float acc0 = bvs[c0i], acc1 = bvs[c0i + 1];
        const float* vd = Vb + (size_t)d * HCDIM + h * CH;
#pragma unroll
        for (int j = 0; j < 16; ++j) {
            float vj = vd[j];
            float a = st[512 + h * 16 + j];
            acc0 += vj * wv1s[j * 16 + c0i] + a * wv2s[j * 16 + c0i];
            acc1 += vj * wv1s[j * 16 + c0i + 1] + a * wv2s[j * 16 + c0i + 1];
        }
#pragma unroll
        for (int k = 0; k < 64; ++k) {
            float wv = st[h * 64 + k];
            acc0 += wv * w3s[k * 128 + h * 16 + c0i];
            acc1 += wv * w3s[k * 128 + h * 16 + c0i + 1];
        }
        aggout[(size_t)d * HCDIM + h * CH + c0i] = acc0;
        aggout[(size_t)d * HCDIM + h * CH + c0i + 1] = acc1;
    }
}

// ---------------- layernorm (+ residual), in-place, one wave per row ----------------
__global__ __launch_bounds__(256) void ln_res_kernel(
    float* __restrict__ y, const float* __restrict__ g, const float* __restrict__ b,
    const float* __restrict__ res, int rows, int w)
{
    int wave = threadIdx.x >> 6;
    int lane = threadIdx.x & 63;
    int nw = blockDim.x >> 6;
    for (int r = blockIdx.x * nw + wave; r < rows; r += gridDim.x * nw) {
        size_t base = (size_t)r * w;
        float v0 = y[base + lane];
        float v1 = (w == 128) ? y[base + 64 + lane] : 0.f;
        float s = v0 + v1;
#pragma unroll
        for (int o = 32; o; o >>= 1) s += __shfl_xor(s, o);
        float m = s / (float)w;
        float d0 = v0 - m;
        float d1 = (w == 128) ? (v1 - m) : 0.f;
        float q = d0 * d0 + d1 * d1;
#pragma unroll
        for (int o = 32; o; o >>= 1) q += __shfl_xor(q, o);
        float inv = rsqrtf(q / (float)w + 1e-5f);
        y[base + lane] = d0 * inv * g[lane] + b[lane] + res[base + lane];
        if (w == 128)
            y[base + 64 + lane] = d1 * inv * g[64 + lane] + b[64 + lane] + res[base + 64 + lane];
    }
}

// ---------------- batchnorm stats ----------------
__global__ __launch_bounds__(256) void bn_stats_kernel(
    const float* __restrict__ y, float* __restrict__ colsum, float* __restrict__ colsq,
    int rows, int cols)
{
    __shared__ float ss[256], sq[256];
    int tid = threadIdx.x;
    int col = tid % cols;
    int rsub = tid / cols;
    int rstep = blockDim.x / cols;
    float ls = 0.f, lq = 0.f;
    for (int r = blockIdx.x * rstep + rsub; r < rows; r += gridDim.x * rstep) {
        float v = y[(size_t)r * cols + col];
        ls += v;
        lq += v * v;
    }
    ss[tid] = ls;
    sq[tid] = lq;
    __syncthreads();
    if (tid < cols) {
        for (int o = cols; o < 256; o += cols) { ls += ss[tid + o]; lq += sq[tid + o]; }
        atomicAdd(&colsum[tid], ls);
        atomicAdd(&colsq[tid], lq);
    }
}

// ---------------- batchnorm apply + residual + softplus -> output ----------------
__global__ __launch_bounds__(256) void bn_apply_softplus_kernel(
    const float* __restrict__ y, const float* __restrict__ res,
    const float* __restrict__ colsum, const float* __restrict__ colsq,
    const float* __restrict__ g, const float* __restrict__ b,
    float* __restrict__ out, int rows, int cols)
{
    int idx = blockIdx.x * blockDim.x + threadIdx.x;
    int n = rows * cols;
    if (idx >= n) return;
    int c = idx % cols;
    float m = colsum[c] / (float)rows;
    float var = colsq[c] / (float)rows - m * m;
    float inv = rsqrtf(var + 1e-5f);
    float v = (y[idx] - m) * inv * g[c] + b[c] + res[idx];
    out[idx] = softplus_f(v);
}

// ---------------- launcher ----------------

extern "C" void kernel_launch(void* const* d_in, const int* in_sizes, int n_in,
                              void* d_out, int out_size, void* d_ws, size_t ws_size,
                              hipStream_t stream) {
    const float* x         = (const float*)d_in[0];
    const int*   ei        = (const int*)d_in[1];
    const float* edge_attr = (const float*)d_in[2];
    const float* Wq  = (const float*)d_in[3];
    const float* bq  = (const float*)d_in[4];
    const float* Wk  = (const float*)d_in[5];
    const float* bk  = (const float*)d_in[6];
    const float* Wv  = (const float*)d_in[7];
    const float* bv  = (const float*)d_in[8];
    const float* We  = (const float*)d_in[9];
    const float* Wke = (const float*)d_in[10];
    const float* bke = (const float*)d_in[11];
    const float* Wve = (const float*)d_in[12];
    const float* bve = (const float*)d_in[13];
    const float* Wfce = (const float*)d_in[14];
    const float* bfce = (const float*)d_in[15];
    const float* lne_g = (const float*)d_in[16];
    const float* lne_b = (const float*)d_in[17];
    const float* Wfcn = (const float*)d_in[18];
    const float* bfcn = (const float*)d_in[19];
    const float* lnn_g = (const float*)d_in[20];
    const float* lnn_b = (const float*)d_in[21];
    const float* W1n = (const float*)d_in[22];
    const float* b1n = (const float*)d_in[23];
    const float* W2n = (const float*)d_in[24];
    const float* b2n = (const float*)d_in[25];
    const float* W1e = (const float*)d_in[26];
    const float* b1e = (const float*)d_in[27];
    const float* W2e = (const float*)d_in[28];
    const float* b2e = (const float*)d_in[29];
    const float* bnn_g = (const float*)d_in[30];
    const float* bnn_b = (const float*)d_in[31];
    const float* bne_g = (const float*)d_in[32];
    const float* bne_b = (const float*)d_in[33];

    const int* src = ei;
    const int* dst = ei + E_EDGES;

    float* ws = (float*)d_ws;
    const size_t M64   = (size_t)E_EDGES * EDIM;       // 25.6M
    const size_t NODE2 = (size_t)N_NODES * HCDIM;      // 6.4M

    // regionR [0, 25.6M): phase A = Qb|Kb|Vb|eproj_c; phase B = h_n; phase C = h_e
    float* regionR = ws;
    float* Qb  = regionR;
    float* Kb  = regionR + NODE2;
    float* Vb  = regionR + 2 * NODE2;
    float* eproj_c = regionR + 3 * NODE2;              // chunk buffer (ECHUNK x 128)
    float* h_n = regionR;                              // 25.6M (N x 512)
    float* h_e = regionR;                              // 25.6M (FCHUNK x 256)

    // overlayY [25.6M, 51.2M): logits|c0|csr|aggout|y_n|x_out; phase C = y_e
    float* overlayY = ws + M64;
    float* logits = overlayY;                                  // 3.2M (holds alpha later)
    float* c0buf  = logits + (size_t)E_EDGES * HEADS;          // 0.4M
    int*   cnt_i    = (int*)(c0buf + (size_t)N_NODES * HEADS); // 50000
    int*   rowptr_i = cnt_i + N_NODES;                         // 50001
    int*   cursor_i = rowptr_i + N_NODES + 1;                  // 50000
    int*   eidx_i   = cursor_i + N_NODES;                      // 400000
    float* aggout = (float*)(eidx_i + E_EDGES);                // 6.4M
    float* y_n    = aggout + NODE2;                            // 6.4M
    float* x_out  = y_n + NODE2;                               // 6.4M
    float* y_e    = overlayY;                                  // 25.6M (phase C)

    // e_out region [51.2M, 76.8M): A2 parks at its start (dead before e_out written)
    float* e_out = ws + 2 * M64;
    float* A2buf = e_out;                                      // 6.4M, dead after logits

    // tail [76.8M, +)
    float* tail = ws + 3 * M64;
    float* colsum_n = tail;            // 128
    float* colsq_n  = tail + 128;      // 128
    float* colsum_e = tail + 256;      // 64
    float* colsq_e  = tail + 320;      // 64
    float* WeK3  = tail + 384;         // 8192
    float* WeWv3 = WeK3 + 8192;        // 8192

    dim3 blk(256);

    // ---- init ----
    fill_kernel<<<dim3(2), blk, 0, stream>>>(colsum_n, 0.f, 384);
    fill_kernel<<<dim3((N_NODES + 255) / 256), blk, 0, stream>>>((float*)cnt_i, 0.f, N_NODES); // int 0 bits

    // ---- precompute folded weights ----
    wex_kernel<<<dim3(32), blk, 0, stream>>>(We, Wke + 2 * CH * CH, WeK3);
    wex_kernel<<<dim3(32), blk, 0, stream>>>(We, Wve + 2 * CH * CH, WeWv3);

    // ---- QKV projections ----
    gemm_bias_act<<<dim3(HCDIM / 64, (N_NODES + 63) / 64), blk, 0, stream>>>(x, Wq, bq, nullptr, Qb, N_NODES, DIM, HCDIM, 0);
    gemm_bias_act<<<dim3(HCDIM / 64, (N_NODES + 63) / 64), blk, 0, stream>>>(x, Wk, bk, nullptr, Kb, N_NODES, DIM, HCDIM, 0);
    gemm_bias_act<<<dim3(HCDIM / 64, (N_NODES + 63) / 64), blk, 0, stream>>>(x, Wv, bv, nullptr, Vb, N_NODES, DIM, HCDIM, 0);

    // ---- per-node QK precompute ----
    qk_pre_kernel<<<dim3(N_NODES * HCDIM / 256), blk, 0, stream>>>(Qb, Kb, Wke, bke, A2buf, c0buf);

    // ---- CSR build ----
    count_kernel<<<dim3((E_EDGES + 255) / 256), blk, 0, stream>>>(dst, cnt_i);
    scan_kernel<<<dim3(1), dim3(1024), 0, stream>>>(cnt_i, rowptr_i, cursor_i, N_NODES);
    scatter_kernel<<<dim3((E_EDGES + 255) / 256), blk, 0, stream>>>(dst, cursor_i, eidx_i);

    // ---- logits per edge chunk (eproj3 = edge_attr @ WeK3) ----
    for (int e0 = 0; e0 < E_EDGES; e0 += ECHUNK) {
        gemm_bias_act<<<dim3(HCDIM / 64, (ECHUNK + 63) / 64), blk, 0, stream>>>(
            edge_attr + (size_t)e0 * EDIM, WeK3, nullptr, nullptr, eproj_c, ECHUNK, EDIM, HCDIM, 0);
        logits_kernel<<<dim3((ECHUNK * HEADS + 255) / 256), blk, 0, stream>>>(
            Qb, Kb, A2buf, c0buf, eproj_c, src, dst, logits, e0, ECHUNK);
    }

    // ---- per-node softmax + aggregation (no atomics); logits -> alpha ----
    node_attn_kernel<<<dim3(N_NODES / NODE_WAVES), blk, 0, stream>>>(
        Vb, edge_attr, logits, rowptr_i, eidx_i, src, Wve, bve, WeWv3, aggout);

    // ---- e_out = LN((alpha ⊙ eproj) @ Wfce + bfce) + edge_attr ----
    for (int e0 = 0; e0 < E_EDGES; e0 += ECHUNK) {
        gemm_bias_act<<<dim3(HCDIM / 64, (ECHUNK + 63) / 64), blk, 0, stream>>>(
            edge_attr + (size_t)e0 * EDIM, We, nullptr, nullptr, eproj_c, ECHUNK, EDIM, HCDIM, 0);
        gemm_bias_act<<<dim3(EDIM / 64, (ECHUNK + 63) / 64), blk, 0, stream>>>(
            eproj_c, Wfce, bfce, logits + (size_t)e0 * HEADS,
            e_out + (size_t)e0 * EDIM, ECHUNK, HCDIM, EDIM, 0);
    }
    ln_res_kernel<<<dim3(25000), blk, 0, stream>>>(e_out, lne_g, lne_b, edge_attr, E_EDGES, EDIM);

    // ---- node output path ----
    gemm_bias_act<<<dim3(DIM / 64, (N_NODES + 63) / 64), blk, 0, stream>>>(aggout, Wfcn, bfcn, nullptr, x_out, N_NODES, HCDIM, DIM, 0);
    ln_res_kernel<<<dim3(12500), blk, 0, stream>>>(x_out, lnn_g, lnn_b, x, N_NODES, DIM);

    // ---- node FFN + BN + residual + softplus (h_n overlays regionR) ----
    gemm_bias_act<<<dim3(4 * DIM / 64, (N_NODES + 63) / 64), blk, 0, stream>>>(x_out, W1n, b1n, nullptr, h_n, N_NODES, DIM, 4 * DIM, 1);
    gemm_bias_act<<<dim3(DIM / 64, (N_NODES + 63) / 64), blk, 0, stream>>>(h_n, W2n, b2n, nullptr, y_n, N_NODES, 4 * DIM, DIM, 0);
    bn_stats_kernel<<<dim3(256), blk, 0, stream>>>(y_n, colsum_n, colsq_n, N_NODES, DIM);
    {
        int n = N_NODES * DIM;
        bn_apply_softplus_kernel<<<dim3((n + 255) / 256), blk, 0, stream>>>(
            y_n, x_out, colsum_n, colsq_n, bnn_g, bnn_b, (float*)d_out, N_NODES, DIM);
    }

    // ---- edge FFN (chunked; h_e overlays regionR, y_e overlays overlayY) ----
    for (int f0 = 0; f0 < E_EDGES; f0 += FCHUNK) {
        gemm_bias_act<<<dim3(4 * EDIM / 64, (FCHUNK + 63) / 64), blk, 0, stream>>>(
            e_out + (size_t)f0 * EDIM, W1e, b1e, nullptr, h_e, FCHUNK, EDIM, 4 * EDIM, 1);
        gemm_bias_act<<<dim3(EDIM / 64, (FCHUNK + 63) / 64), blk, 0, stream>>>(
            h_e, W2e, b2e, nullptr, y_e + (size_t)f0 * EDIM, FCHUNK, 4 * EDIM, EDIM, 0);
    }
    bn_stats_kernel<<<dim3(256), blk, 0, stream>>>(y_e, colsum_e, colsq_e, E_EDGES, EDIM);
    {
        int n = E_EDGES * EDIM;
        bn_apply_softplus_kernel<<<dim3((n + 255) / 256), blk, 0, stream>>>(
            y_e, e_out, colsum_e, colsq_e, bne_g, bne_b, (float*)d_out + (size_t)N_NODES * DIM, E_EDGES, EDIM);
    }
}